// Round 1
// baseline (251.435 us; speedup 1.0000x reference)
//
#include <hip/hip_runtime.h>
#include <math.h>

// Problem constants (match reference)
#define MAXF 512
#define BZ   32
#define DD   1024
#define HH   16
#define OO   4
#define SS   64
#define FCH  4096

// ---------------------------------------------------------------------------
// Kernel A: per (b,h) block: logits -> softmax -> attn (to ws, (b,h,o,f)
// layout) and h_vid accumulation -> hcat (B, O*H*S) layout.
// ---------------------------------------------------------------------------
__global__ __launch_bounds__(256) void attn_kernel(
    const float* __restrict__ x, const int* __restrict__ num_frames,
    const float* __restrict__ query, float* __restrict__ ws_attn,
    float* __restrict__ ws_hcat)
{
    __shared__ float sq[OO * SS];                       // queries for this h
    __shared__ __align__(16) float att[MAXF][OO];       // logits -> attn
    __shared__ float red[4][OO * SS];                   // cross-wave partials

    const int tid = threadIdx.x;
    const int bh  = blockIdx.x;          // b*16 + h
    const int b   = bh >> 4;
    const int h   = bh & 15;
    const int nf  = num_frames[b];

    // load queries for this head: sq[o*64+s]
    {
        int o = tid >> 6, s = tid & 63;
        sq[tid] = query[(size_t)(o * HH + h) * SS + s];
    }
    __syncthreads();

    // ---- phase 1: logits; thread owns frames tid and tid+256 ----
    {
        const float4* sq4 = (const float4*)sq;
        const float4* fr0 = (const float4*)(x + ((size_t)tid * BZ + b) * DD + h * SS);
        const float4* fr1 = (const float4*)(x + ((size_t)(tid + 256) * BZ + b) * DD + h * SS);
        float a0[4] = {0.f, 0.f, 0.f, 0.f};
        float a1[4] = {0.f, 0.f, 0.f, 0.f};
        #pragma unroll
        for (int i = 0; i < 16; ++i) {
            float4 v0 = fr0[i];
            float4 v1 = fr1[i];
            #pragma unroll
            for (int o = 0; o < 4; ++o) {
                float4 q = sq4[o * 16 + i];
                a0[o] += v0.x * q.x + v0.y * q.y + v0.z * q.z + v0.w * q.w;
                a1[o] += v1.x * q.x + v1.y * q.y + v1.z * q.z + v1.w * q.w;
            }
        }
        #pragma unroll
        for (int o = 0; o < 4; ++o) {
            att[tid][o]       = (tid < nf)       ? a0[o] * 0.125f : -50.0f;
            att[tid + 256][o] = (tid + 256 < nf) ? a1[o] * 0.125f : -50.0f;
        }
    }
    __syncthreads();

    const int wv = tid >> 6, lane = tid & 63;

    // ---- softmax over F: wave wv handles query o = wv ----
    {
        const int o = wv;
        float l[8];
        float m = -1e30f;
        #pragma unroll
        for (int k = 0; k < 8; ++k) {
            l[k] = att[lane + 64 * k][o];
            m = fmaxf(m, l[k]);
        }
        #pragma unroll
        for (int d = 32; d; d >>= 1) m = fmaxf(m, __shfl_xor(m, d, 64));
        float s = 0.f;
        #pragma unroll
        for (int k = 0; k < 8; ++k) {
            l[k] = expf(l[k] - m);
            s += l[k];
        }
        #pragma unroll
        for (int d = 32; d; d >>= 1) s += __shfl_xor(s, d, 64);
        const float inv = 1.0f / s;
        #pragma unroll
        for (int k = 0; k < 8; ++k) {
            float a = l[k] * inv;
            att[lane + 64 * k][o] = a;   // unmasked attn (output semantics)
            ws_attn[((size_t)bh * OO + o) * MAXF + lane + 64 * k] = a;
        }
    }
    __syncthreads();

    // ---- phase 2: h_vid[o][s] = sum_{f<nf} attn[o][f] * x[f][b][h*64+s] ----
    {
        float acc[4] = {0.f, 0.f, 0.f, 0.f};
        const int f0 = wv * 128;
        const int f1 = min(nf, f0 + 128);
        for (int f = f0; f < f1; ++f) {
            float v  = x[((size_t)f * BZ + b) * DD + h * SS + lane];
            float4 a = *(const float4*)&att[f][0];   // wave-uniform broadcast
            acc[0] += a.x * v;
            acc[1] += a.y * v;
            acc[2] += a.z * v;
            acc[3] += a.w * v;
        }
        #pragma unroll
        for (int o = 0; o < 4; ++o) red[wv][o * 64 + lane] = acc[o];
    }
    __syncthreads();
    {
        int o = tid >> 6, s = tid & 63;
        float v = red[0][o * 64 + s] + red[1][o * 64 + s] +
                  red[2][o * 64 + s] + red[3][o * 64 + s];
        // h_cat[b][o*H*S + h*S + s]
        ws_hcat[(size_t)b * (OO * HH * SS) + o * (HH * SS) + h * SS + s] = v;
    }
}

// ---------------------------------------------------------------------------
// Kernel B: transpose ws_attn (bh, o, f) -> d_out attn (o, f, bh)
// ---------------------------------------------------------------------------
__global__ __launch_bounds__(256) void attn_tr_kernel(
    const float* __restrict__ ws_attn, float* __restrict__ attn_out)
{
    __shared__ float tile[64][65];
    const int o  = blockIdx.z;
    const int f0 = blockIdx.x * 64;
    const int g0 = blockIdx.y * 64;   // bh tile base
    const int c  = threadIdx.x & 63;
    const int r4 = threadIdx.x >> 6;
    for (int r = r4; r < 64; r += 4)
        tile[r][c] = ws_attn[((size_t)(g0 + r) * OO + o) * MAXF + f0 + c];
    __syncthreads();
    for (int r = r4; r < 64; r += 4)
        attn_out[((size_t)o * MAXF + f0 + r) * (BZ * HH) + g0 + c] = tile[c][r];
}

// ---------------------------------------------------------------------------
// Kernel C: hid_raw = hcat(32x4096) @ W1(4096x4096), split over d, atomics.
// grid (16 j-tiles, 32 d-parts), 256 threads; thread owns column j, 32 b accs.
// ---------------------------------------------------------------------------
__global__ __launch_bounds__(256) void fc1_kernel(
    const float* __restrict__ hcat, const float* __restrict__ W1,
    float* __restrict__ hid)
{
    __shared__ __align__(16) float hch[128 * 32];   // [d][b]
    const int tid = threadIdx.x;
    const int j   = blockIdx.x * 256 + tid;
    const int d0  = blockIdx.y * 128;

    // stage hcat chunk (coalesced global read; LDS write conflicts are tiny)
    #pragma unroll
    for (int k = 0; k < 16; ++k) {
        int idx = tid + k * 256;
        int d = idx & 127, bb = idx >> 7;
        hch[d * 32 + bb] = hcat[(size_t)bb * FCH + d0 + d];
    }
    __syncthreads();

    float acc[32];
    #pragma unroll
    for (int b = 0; b < 32; ++b) acc[b] = 0.f;

    for (int d = 0; d < 128; ++d) {
        float w = W1[(size_t)(d0 + d) * FCH + j];
        const float4* hr = (const float4*)&hch[d * 32];
        #pragma unroll
        for (int b4 = 0; b4 < 8; ++b4) {
            float4 hv = hr[b4];   // wave-uniform b128 broadcast
            acc[b4 * 4 + 0] += hv.x * w;
            acc[b4 * 4 + 1] += hv.y * w;
            acc[b4 * 4 + 2] += hv.z * w;
            acc[b4 * 4 + 3] += hv.w * w;
        }
    }
    #pragma unroll
    for (int b = 0; b < 32; ++b)
        atomicAdd(&hid[(size_t)b * FCH + j], acc[b]);
}

// ---------------------------------------------------------------------------
// Kernel D: out = relu(hid + b1) @ W2 + b2 ; one block per b.
// ---------------------------------------------------------------------------
__global__ __launch_bounds__(256) void fc2_kernel(
    const float* __restrict__ hid, const float* __restrict__ b1,
    const float* __restrict__ W2, const float* __restrict__ b2,
    float* __restrict__ out)
{
    __shared__ float red[4][4];
    const int b = blockIdx.x, tid = threadIdx.x;
    float a0 = 0.f, a1 = 0.f, a2 = 0.f, a3 = 0.f;
    for (int j = tid; j < FCH; j += 256) {
        float hv = hid[(size_t)b * FCH + j] + b1[j];
        hv = fmaxf(hv, 0.0f);
        float4 w = ((const float4*)W2)[j];
        a0 += hv * w.x; a1 += hv * w.y; a2 += hv * w.z; a3 += hv * w.w;
    }
    #pragma unroll
    for (int d = 32; d; d >>= 1) {
        a0 += __shfl_xor(a0, d, 64);
        a1 += __shfl_xor(a1, d, 64);
        a2 += __shfl_xor(a2, d, 64);
        a3 += __shfl_xor(a3, d, 64);
    }
    const int wv = tid >> 6, lane = tid & 63;
    if (lane == 0) { red[wv][0] = a0; red[wv][1] = a1; red[wv][2] = a2; red[wv][3] = a3; }
    __syncthreads();
    if (tid < 4) {
        float s = red[0][tid] + red[1][tid] + red[2][tid] + red[3][tid] + b2[tid];
        out[b * OO + tid] = s;
    }
}

// ---------------------------------------------------------------------------
extern "C" void kernel_launch(void* const* d_in, const int* in_sizes, int n_in,
                              void* d_out, int out_size, void* d_ws, size_t ws_size,
                              hipStream_t stream)
{
    const float* x          = (const float*)d_in[0];
    const int*   num_frames = (const int*)  d_in[1];
    const float* query      = (const float*)d_in[2];
    const float* W1         = (const float*)d_in[3];
    const float* b1         = (const float*)d_in[4];
    const float* W2         = (const float*)d_in[5];
    const float* b2         = (const float*)d_in[6];

    float* out      = (float*)d_out;           // (B, O) = 128 floats
    float* attn_out = out + BZ * OO;           // (O, F, B, H) = 1048576 floats

    float* ws       = (float*)d_ws;
    float* ws_attn  = ws;                      // (bh, o, f): 1048576 floats
    float* ws_hcat  = ws + 1048576;            // (B, 4096):  131072 floats
    float* ws_hid   = ws + 1048576 + 131072;   // (B, 4096):  131072 floats

    hipMemsetAsync(ws_hid, 0, (size_t)BZ * FCH * sizeof(float), stream);

    attn_kernel<<<BZ * HH, 256, 0, stream>>>(x, num_frames, query, ws_attn, ws_hcat);
    attn_tr_kernel<<<dim3(MAXF / 64, (BZ * HH) / 64, OO), 256, 0, stream>>>(ws_attn, attn_out);
    fc1_kernel<<<dim3(FCH / 256, FCH / 128), 256, 0, stream>>>(ws_hcat, W1, ws_hid);
    fc2_kernel<<<BZ, 256, 0, stream>>>(ws_hid, b1, W2, b2, out);
}

// Round 2
// 243.908 us; speedup vs baseline: 1.0309x; 1.0309x over previous
//
#include <hip/hip_runtime.h>
#include <math.h>

// Problem constants (match reference)
#define MAXF 512
#define BZ   32
#define DD   1024
#define HH   16
#define OO   4
#define SS   64
#define FCH  4096

// ---------------------------------------------------------------------------
// K1: logits[bh][o][f] = (f < nf) ? (x[f,b,h,:] . q[o,h,:]) / 8 : -50
// grid: 4096 blocks = 512 bh * 8 f-chunks; 64x64 x-tile staged in LDS.
// ---------------------------------------------------------------------------
__global__ __launch_bounds__(256) void logits_kernel(
    const float* __restrict__ x, const int* __restrict__ num_frames,
    const float* __restrict__ query, float* __restrict__ logits)
{
    __shared__ float tile[64][65];   // [f][s], +1 pad -> 2-way conflicts (free)
    __shared__ float sq[OO * SS];

    const int tid   = threadIdx.x;
    const int bh    = blockIdx.x >> 3;
    const int fc    = blockIdx.x & 7;
    const int b     = bh >> 4, h = bh & 15;
    const int nf    = num_frames[b];
    const int fbase = fc * 64;

    {   // queries for this head
        int o = tid >> 6, s = tid & 63;
        sq[tid] = query[(size_t)(o * HH + h) * SS + s];
    }
    // stage x tile: 16-lane groups cover one frame's 64 floats (4x256B/instr)
    #pragma unroll
    for (int k = 0; k < 4; ++k) {
        int idx = tid + k * 256;
        int f = idx >> 4, c4 = (idx & 15) * 4;
        const float4 v = *(const float4*)(x + ((size_t)(fbase + f) * BZ + b) * DD + h * SS + c4);
        tile[f][c4 + 0] = v.x; tile[f][c4 + 1] = v.y;
        tile[f][c4 + 2] = v.z; tile[f][c4 + 3] = v.w;
    }
    __syncthreads();

    const int o = tid >> 6, f = tid & 63;
    float dot = 0.f;
    #pragma unroll
    for (int s = 0; s < 64; ++s)
        dot += tile[f][s] * sq[o * 64 + s];   // sq: wave-uniform broadcast

    float lg = (fbase + f < nf) ? dot * 0.125f : -50.0f;
    logits[((size_t)bh * OO + o) * MAXF + fbase + f] = lg;   // coalesced
}

// ---------------------------------------------------------------------------
// K2: weighted sum. Each block (bh, f-chunk) reads the FULL logit row (L2-hot),
// computes softmax stats redundantly, accumulates its chunk's contribution to
// hcat via atomics, and (chunk 0 only) writes (m, 1/s) stats for K3.
// ---------------------------------------------------------------------------
__global__ __launch_bounds__(256) void wsum_kernel(
    const float* __restrict__ x, const int* __restrict__ num_frames,
    const float* __restrict__ logits, float* __restrict__ stats,
    float* __restrict__ hcat)
{
    __shared__ float tile[64][65];
    __shared__ float lrow[OO][MAXF];
    __shared__ float attc[OO][64];

    const int tid   = threadIdx.x;
    const int bh    = blockIdx.x >> 3;
    const int fc    = blockIdx.x & 7;
    const int b     = bh >> 4, h = bh & 15;
    const int nf    = num_frames[b];
    const int fbase = fc * 64;

    #pragma unroll
    for (int k = 0; k < 4; ++k) {
        int idx = tid + k * 256;
        int f = idx >> 4, c4 = (idx & 15) * 4;
        const float4 v = *(const float4*)(x + ((size_t)(fbase + f) * BZ + b) * DD + h * SS + c4);
        tile[f][c4 + 0] = v.x; tile[f][c4 + 1] = v.y;
        tile[f][c4 + 2] = v.z; tile[f][c4 + 3] = v.w;
    }
    #pragma unroll
    for (int k = 0; k < 8; ++k) {
        int idx = tid + k * 256;
        int o = idx >> 9, f = idx & 511;
        lrow[o][f] = logits[((size_t)bh * OO + o) * MAXF + f];   // coalesced
    }
    __syncthreads();

    const int wv = tid >> 6, lane = tid & 63;
    {   // wave wv owns query o = wv: softmax stats over the full 512-row
        const int o = wv;
        float l[8], m = -1e30f;
        #pragma unroll
        for (int k = 0; k < 8; ++k) { l[k] = lrow[o][lane + 64 * k]; m = fmaxf(m, l[k]); }
        #pragma unroll
        for (int d = 32; d; d >>= 1) m = fmaxf(m, __shfl_xor(m, d, 64));
        float s = 0.f;
        #pragma unroll
        for (int k = 0; k < 8; ++k) s += expf(l[k] - m);
        #pragma unroll
        for (int d = 32; d; d >>= 1) s += __shfl_xor(s, d, 64);
        const float inv = 1.0f / s;
        // chunk-normalized attn; ZERO for padded frames (h_pad semantics)
        float lc = lrow[o][fbase + lane];
        attc[o][lane] = (fbase + lane < nf) ? expf(lc - m) * inv : 0.f;
        if (fc == 0 && lane == 0) {
            stats[(bh * OO + o) * 2 + 0] = m;
            stats[(bh * OO + o) * 2 + 1] = inv;
        }
    }
    __syncthreads();

    // MAC: thread (o=wv, s=lane): sum over 64 chunk frames
    float acc = 0.f;
    #pragma unroll
    for (int f = 0; f < 64; ++f)
        acc += attc[wv][f] * tile[f][lane];   // attc: broadcast; tile: 2-way

    atomicAdd(&hcat[(size_t)b * (OO * HH * SS) + wv * (HH * SS) + h * SS + lane], acc);
}

// ---------------------------------------------------------------------------
// K3: attn output = transpose + normalize: attn[o][f][bh] = exp(l - m) * inv
// ---------------------------------------------------------------------------
__global__ __launch_bounds__(256) void attn_out_kernel(
    const float* __restrict__ logits, const float* __restrict__ stats,
    float* __restrict__ attn_out)
{
    __shared__ float tile[64][65];
    __shared__ float sm[64], sv[64];
    const int o     = blockIdx.z;
    const int fbase = blockIdx.x * 64;
    const int gbase = blockIdx.y * 64;   // bh tile base
    const int c  = threadIdx.x & 63;
    const int r4 = threadIdx.x >> 6;

    if (threadIdx.x < 64) {
        sm[threadIdx.x] = stats[((gbase + threadIdx.x) * OO + o) * 2 + 0];
        sv[threadIdx.x] = stats[((gbase + threadIdx.x) * OO + o) * 2 + 1];
    }
    for (int r = r4; r < 64; r += 4)
        tile[r][c] = logits[((size_t)(gbase + r) * OO + o) * MAXF + fbase + c];
    __syncthreads();
    for (int r = r4; r < 64; r += 4)
        attn_out[((size_t)o * MAXF + fbase + r) * (BZ * HH) + gbase + c] =
            expf(tile[c][r] - sm[c]) * sv[c];
}

// ---------------------------------------------------------------------------
// K4: fc1: hid[b][j] += sum_d hcat[b][d] * W1[d][j]
// grid (8 j-tiles of 512, 32 d-parts of 128); thread: 2 cols, 32 batches.
// ---------------------------------------------------------------------------
__global__ __launch_bounds__(256) void fc1_kernel(
    const float* __restrict__ hcat, const float* __restrict__ W1,
    float* __restrict__ hid)
{
    __shared__ __align__(16) float hch[128][36];   // [d][b], pad 4 keeps b128 align
    const int tid = threadIdx.x;
    const int jt  = blockIdx.x;           // 0..7
    const int d0  = blockIdx.y * 128;     // 0..31
    const int j   = jt * 512 + tid * 2;

    #pragma unroll
    for (int k = 0; k < 16; ++k) {
        int idx = tid + k * 256;          // 4096 = 32 b * 128 d
        int bb = idx >> 7, d = idx & 127;
        hch[d][bb] = hcat[(size_t)bb * FCH + d0 + d];   // coalesced global read
    }
    __syncthreads();

    float2 acc[32];
    #pragma unroll
    for (int i = 0; i < 32; ++i) acc[i] = make_float2(0.f, 0.f);

    for (int d = 0; d < 128; ++d) {
        const float2 w = *(const float2*)(W1 + (size_t)(d0 + d) * FCH + j);
        const float4* hp = (const float4*)&hch[d][0];   // 16B-aligned (36*4=144)
        #pragma unroll
        for (int b4 = 0; b4 < 8; ++b4) {
            float4 hv = hp[b4];   // wave-uniform b128 broadcast
            acc[b4 * 4 + 0].x += hv.x * w.x; acc[b4 * 4 + 0].y += hv.x * w.y;
            acc[b4 * 4 + 1].x += hv.y * w.x; acc[b4 * 4 + 1].y += hv.y * w.y;
            acc[b4 * 4 + 2].x += hv.z * w.x; acc[b4 * 4 + 2].y += hv.z * w.y;
            acc[b4 * 4 + 3].x += hv.w * w.x; acc[b4 * 4 + 3].y += hv.w * w.y;
        }
    }
    #pragma unroll
    for (int bb = 0; bb < 32; ++bb) {
        atomicAdd(&hid[(size_t)bb * FCH + j],     acc[bb].x);
        atomicAdd(&hid[(size_t)bb * FCH + j + 1], acc[bb].y);
    }
}

// ---------------------------------------------------------------------------
// K5: out = relu(hid + b1) @ W2 + b2 ; one block per b, float4 throughout.
// ---------------------------------------------------------------------------
__global__ __launch_bounds__(256) void fc2_kernel(
    const float* __restrict__ hid, const float* __restrict__ b1,
    const float* __restrict__ W2, const float* __restrict__ b2,
    float* __restrict__ out)
{
    __shared__ float red[4][4];
    const int b = blockIdx.x, tid = threadIdx.x;
    float a0 = 0.f, a1 = 0.f, a2 = 0.f, a3 = 0.f;
    #pragma unroll
    for (int k = 0; k < 4; ++k) {
        int j4 = tid + k * 256;   // j = j4*4
        float4 hv = ((const float4*)(hid + (size_t)b * FCH))[j4];
        float4 bv = ((const float4*)b1)[j4];
        float h0 = fmaxf(hv.x + bv.x, 0.f), h1 = fmaxf(hv.y + bv.y, 0.f);
        float h2 = fmaxf(hv.z + bv.z, 0.f), h3 = fmaxf(hv.w + bv.w, 0.f);
        float4 w0 = ((const float4*)W2)[j4 * 4 + 0];
        float4 w1 = ((const float4*)W2)[j4 * 4 + 1];
        float4 w2 = ((const float4*)W2)[j4 * 4 + 2];
        float4 w3 = ((const float4*)W2)[j4 * 4 + 3];
        a0 += h0 * w0.x + h1 * w1.x + h2 * w2.x + h3 * w3.x;
        a1 += h0 * w0.y + h1 * w1.y + h2 * w2.y + h3 * w3.y;
        a2 += h0 * w0.z + h1 * w1.z + h2 * w2.z + h3 * w3.z;
        a3 += h0 * w0.w + h1 * w1.w + h2 * w2.w + h3 * w3.w;
    }
    #pragma unroll
    for (int d = 32; d; d >>= 1) {
        a0 += __shfl_xor(a0, d, 64);
        a1 += __shfl_xor(a1, d, 64);
        a2 += __shfl_xor(a2, d, 64);
        a3 += __shfl_xor(a3, d, 64);
    }
    const int wv = tid >> 6, lane = tid & 63;
    if (lane == 0) { red[wv][0] = a0; red[wv][1] = a1; red[wv][2] = a2; red[wv][3] = a3; }
    __syncthreads();
    if (tid < 4) {
        float s = red[0][tid] + red[1][tid] + red[2][tid] + red[3][tid] + b2[tid];
        out[b * OO + tid] = s;
    }
}

// ---------------------------------------------------------------------------
extern "C" void kernel_launch(void* const* d_in, const int* in_sizes, int n_in,
                              void* d_out, int out_size, void* d_ws, size_t ws_size,
                              hipStream_t stream)
{
    const float* x          = (const float*)d_in[0];
    const int*   num_frames = (const int*)  d_in[1];
    const float* query      = (const float*)d_in[2];
    const float* W1         = (const float*)d_in[3];
    const float* b1         = (const float*)d_in[4];
    const float* W2         = (const float*)d_in[5];
    const float* b2         = (const float*)d_in[6];

    float* out      = (float*)d_out;           // (B, O) = 128 floats
    float* attn_out = out + BZ * OO;           // (O, F, B*H) = 1048576 floats

    float* ws        = (float*)d_ws;
    float* ws_logits = ws;                         // 1,048,576 floats (4 MB)
    float* ws_stats  = ws + 1048576;               // 4,096 floats (m, 1/s)
    float* ws_hcat   = ws + 1048576 + 4096;        // 131,072 floats
    float* ws_hid    = ws_hcat + 131072;           // 131,072 floats

    // hcat & hid are atomic targets -> zero both (adjacent, one memset)
    hipMemsetAsync(ws_hcat, 0, (size_t)2 * BZ * FCH * sizeof(float), stream);

    logits_kernel  <<<4096, 256, 0, stream>>>(x, num_frames, query, ws_logits);
    wsum_kernel    <<<4096, 256, 0, stream>>>(x, num_frames, ws_logits, ws_stats, ws_hcat);
    attn_out_kernel<<<dim3(8, 8, 4), 256, 0, stream>>>(ws_logits, ws_stats, attn_out);
    fc1_kernel     <<<dim3(8, 32), 256, 0, stream>>>(ws_hcat, W1, ws_hid);
    fc2_kernel     <<<BZ, 256, 0, stream>>>(ws_hid, b1, W2, b2, out);
}